// Round 6
// baseline (356.759 us; speedup 1.0000x reference)
//
#include <hip/hip_runtime.h>
#include <hip/hip_fp16.h>
#include <stdint.h>

// ---------------------------------------------------------------------------
// RuleModel forward. ST-gumbel gate forward == exact one-hot column selector,
// so each h @ gate is a gather with index argmax_i(w[i,j]+g[i,j]).
// argmax reads are pinned at ~10.8 GB/s/CU across 6 concurrency configs
// (rounds 0-5): per-CU memory-system limit, not ILP/TLP/BW. This round:
//  (a) forward_kernel: split the fp16-packed h table into hx/hy uint arrays
//      -- 8B gathers at stride-8 hit only even/odd banks (~8-way conflict);
//      split 4B arrays spread all 32 banks (~4-way, ~2x cheaper gathers).
//  (b) x loaded nontemporal in forward: stop evicting w+g (218MB, nearly
//      LLC-resident) with the 67MB x stream -> argmax LLC hit rate up.
// Pipeline: memset(80KB) -> argmax_fused (64-row chunks, LDS sub-merge,
// atomicMax into 10,240-slot packed table) -> convert_fb -> forward.
// ---------------------------------------------------------------------------

struct GatePtrs {
    const float* w[12];
    const float* g[12];
};

__device__ __forceinline__ unsigned int sortkey(float f) {
    unsigned int u = __float_as_uint(f);
    return u ^ ((u & 0x80000000u) ? 0xFFFFFFFFu : 0x80000000u);
}

// ---------------- fused argmax: block argmax + global atomicMax -------------
// packed layout (u64, 10240 entries): offs[layer] + slot*dout + col.
// value = (sortkey(best) << 32) | (0xFFFFFFFF - best_row)  -> max == best key,
// ties resolved to the SMALLEST row (matches jnp.argmax first-index).
// Flat grid, ONE 512-thread block per (gate, 64-row chunk):
//   L0: blocks [0,68)    = 4 gates x 17 chunks (2 subs x 32 rows, 256 c4)
//   L1: blocks [68,264)  = 4 gates x 49 chunks (2 subs x 32 rows, 256 c4)
//   L2: blocks [264,588) = 4 gates x 81 chunks (4 subs x 16 rows, 128 c4)
__global__ __launch_bounds__(512) void argmax_fused(GatePtrs gp,
                                                    unsigned long long* __restrict__ packed) {
    __shared__ unsigned long long red[1536];   // (subs-1) x cols4 x 4, max 12 KB
    const int dins[3] = {1026, 3074, 5122};
    const int offs[3] = {0, 4096, 8192};
    int bid = blockIdx.x, tid = threadIdx.x;
    int layer, slot, chunk;
    if (bid < 68)       { layer = 0; slot = bid / 17;  chunk = bid - slot * 17; }
    else if (bid < 264) { layer = 1; int r = bid - 68;  slot = r / 49; chunk = r - slot * 49; }
    else                { layer = 2; int r = bid - 264; slot = r / 81; chunk = r - slot * 81; }
    const int gate  = layer * 4 + slot;
    const int din   = dins[layer];
    const int dout  = (layer == 2) ? 512 : 1024;
    const int shift = (layer == 2) ? 7 : 8;     // log2(cols4)
    const int cols4 = 1 << shift;
    const int subs  = 512 >> shift;             // 2 (L0/L1) or 4 (L2)
    const int rps   = 64 / subs;                // rows per sub: 32 or 16
    const int sub   = tid >> shift;
    const int c4    = tid & (cols4 - 1);
    const int s4    = dout >> 2;                // float4s per row
    const int rbeg  = chunk * 64 + sub * rps;
    const int rend  = min(rbeg + rps, din);     // tail chunks: some subs empty

    const float4* __restrict__ wp = (const float4*)gp.w[gate] + (size_t)rbeg * s4 + c4;
    const float4* __restrict__ gq = (const float4*)gp.g[gate] + (size_t)rbeg * s4 + c4;
    // Empty subs keep the -3.4e38 init; sortkey(-3.4e38) is far below any
    // real w+g key (inputs are O(10)), so fake entries never win the merge.
    float bx = -3.4e38f, by = bx, bz = bx, bw = bx;
    int ix = rbeg, iy = rbeg, iz = rbeg, iw = rbeg;
    #pragma unroll 8
    for (int i = rbeg; i < rend; ++i) {
        float4 wv = wp[(size_t)(i - rbeg) * s4];
        float4 gv = gq[(size_t)(i - rbeg) * s4];
        float vx = wv.x + gv.x, vy = wv.y + gv.y;
        float vz = wv.z + gv.z, vw = wv.w + gv.w;
        if (vx > bx) { bx = vx; ix = i; }       // strict > keeps first row
        if (vy > by) { by = vy; iy = i; }
        if (vz > bz) { bz = vz; iz = i; }
        if (vw > bw) { bw = vw; iw = i; }
    }
    unsigned long long e0 = ((unsigned long long)sortkey(bx) << 32) | (unsigned int)ix;
    unsigned long long e1 = ((unsigned long long)sortkey(by) << 32) | (unsigned int)iy;
    unsigned long long e2 = ((unsigned long long)sortkey(bz) << 32) | (unsigned int)iz;
    unsigned long long e3 = ((unsigned long long)sortkey(bw) << 32) | (unsigned int)iw;

    if (sub != 0) {
        unsigned long long* r = red + ((size_t)(sub - 1) * cols4 + c4) * 4;
        r[0] = e0; r[1] = e1; r[2] = e2; r[3] = e3;
    }
    __syncthreads();
    if (sub == 0) {
        // merge ascending-row sub-results; strict > keeps the lowest row on
        // ties (sub s covers strictly lower rows than sub s+1)
        for (int s = 1; s < subs; ++s) {
            const unsigned long long* r = red + ((size_t)(s - 1) * cols4 + c4) * 4;
            unsigned long long o0 = r[0], o1 = r[1], o2 = r[2], o3 = r[3];
            if ((unsigned int)(o0 >> 32) > (unsigned int)(e0 >> 32)) e0 = o0;
            if ((unsigned int)(o1 >> 32) > (unsigned int)(e1 >> 32)) e1 = o1;
            if ((unsigned int)(o2 >> 32) > (unsigned int)(e2 >> 32)) e2 = o2;
            if ((unsigned int)(o3 >> 32) > (unsigned int)(e3 >> 32)) e3 = o3;
        }
        // flip idx to (0xFFFFFFFF - idx): atomicMax then prefers SMALLER rows
        // on equal keys, matching the ordered-merge semantics above.
        unsigned long long* dst = packed + offs[layer] + (size_t)slot * dout + 4 * c4;
        atomicMax(dst + 0, (e0 & 0xFFFFFFFF00000000ull) | (0xFFFFFFFFu - (unsigned int)e0));
        atomicMax(dst + 1, (e1 & 0xFFFFFFFF00000000ull) | (0xFFFFFFFFu - (unsigned int)e1));
        atomicMax(dst + 2, (e2 & 0xFFFFFFFF00000000ull) | (0xFFFFFFFFu - (unsigned int)e2));
        atomicMax(dst + 3, (e3 & 0xFFFFFFFF00000000ull) | (0xFFFFFFFFu - (unsigned int)e3));
    }
}

// ---------------- fallback: atomic argmax (small ws) ------------------------
__global__ __launch_bounds__(256) void argmax_atomic(GatePtrs gp,
                                                     unsigned long long* __restrict__ packed) {
    const int dins[3]  = {1026, 3074, 5122};
    const int douts[3] = {1024, 1024, 512};
    const int offs[3]  = {0, 4096, 8192};
    int gate = blockIdx.z, layer = gate >> 2;
    int din = dins[layer], dout = douts[layer];
    int c2 = blockIdx.x * 256 + threadIdx.x;
    int r0 = blockIdx.y * 64;
    if (2 * c2 >= dout || r0 >= din) return;
    int r1 = min(r0 + 64, din);
    const float* __restrict__ w = gp.w[gate];
    const float* __restrict__ g = gp.g[gate];
    float bx = -3.4e38f, by = -3.4e38f;
    int rx = r0, ry = r0;
    #pragma unroll 8
    for (int i = r0; i < r1; ++i) {
        float2 wv = *(const float2*)(w + (size_t)i * dout + 2 * c2);
        float2 gv = *(const float2*)(g + (size_t)i * dout + 2 * c2);
        float vx = wv.x + gv.x, vy = wv.y + gv.y;
        if (vx > bx) { bx = vx; rx = i; }
        if (vy > by) { by = vy; ry = i; }
    }
    unsigned long long* dst = packed + offs[layer] + (gate & 3) * dout + 2 * c2;
    atomicMax(dst, ((unsigned long long)sortkey(bx) << 32)
                   | (unsigned long long)(0xFFFFFFFFu - (unsigned int)rx));
    atomicMax(dst + 1, ((unsigned long long)sortkey(by) << 32)
                   | (unsigned long long)(0xFFFFFFFFu - (unsigned int)ry));
}

// ---------------- convert packed -> pf (both paths) -------------------------
__global__ __launch_bounds__(256) void convert_fb(const unsigned long long* __restrict__ packed,
                                                  ushort2* __restrict__ pf) {
    int i = blockIdx.x * 256 + threadIdx.x;
    if (i >= 5120) return;
    int l    = (i < 2048) ? 0 : ((i < 4096) ? 1 : 2);
    int half = (l == 2) ? 512 : 1024;
    int r    = i - l * 2048;
    int type = (r >= half) ? 1 : 0;
    int g    = r - type * half;
    int o1   = l * 4096 + 2 * type * half + g;
    int o2   = o1 + half;
    unsigned int i1 = 0xFFFFFFFFu - (unsigned int)(packed[o1] & 0xFFFFFFFFull);
    unsigned int i2 = 0xFFFFFFFFu - (unsigned int)(packed[o2] & 0xFFFFFFFFull);
    pf[i] = make_ushort2((unsigned short)i1, (unsigned short)i2);
}

// ---------------- forward: 4 rows/block, fp16 h in SPLIT LDS arrays ---------
// hx[s]/hy[s] hold rows 0,1 / 2,3 of feature s as __half2. Split 4B arrays
// put random gathers on all 32 banks (uint2-at-stride-8 confined .x to the
// 16 even banks -> ~8-way conflicts on every ds_read_b64).
__device__ __forceinline__ __half2 bc(unsigned int u) { return __builtin_bit_cast(__half2, u); }
__device__ __forceinline__ unsigned int cb(__half2 h) { return __builtin_bit_cast(unsigned int, h); }

__device__ __forceinline__ uint2 andg(uint2 a, uint2 b) {
    return make_uint2(cb(__hmul2(bc(a.x), bc(b.x))), cb(__hmul2(bc(a.y), bc(b.y))));
}
__device__ __forceinline__ uint2 org(uint2 a, uint2 b) {
    __half2 one = __float2half2_rn(1.0f);
    __half2 lo = __hsub2(one, __hmul2(__hsub2(one, bc(a.x)), __hsub2(one, bc(b.x))));
    __half2 hi = __hsub2(one, __hmul2(__hsub2(one, bc(a.y)), __hsub2(one, bc(b.y))));
    return make_uint2(cb(lo), cb(hi));
}

__global__ __launch_bounds__(512) void forward_kernel(const float* __restrict__ x,
                                                      const float* __restrict__ lin_w,
                                                      const ushort2* __restrict__ pairs,
                                                      float* __restrict__ out) {
    __shared__ unsigned int hx[5122];
    __shared__ unsigned int hy[5122];
    __shared__ float4 red[8];
    const int t  = threadIdx.x;
    const int r0 = blockIdx.x * 4;

#define GAT(s) make_uint2(hx[(s)], hy[(s)])
#define PUT(s, v) do { hx[(s)] = (v).x; hy[(s)] = (v).y; } while (0)

    // nontemporal: x is streamed once; keep it out of the LLC so w+g (218MB,
    // nearly LLC-resident) survive across iterations for argmax_fused.
    float xa = __builtin_nontemporal_load(&x[(size_t)(r0 + 0) * 512 + t]);
    float xb = __builtin_nontemporal_load(&x[(size_t)(r0 + 1) * 512 + t]);
    float xc = __builtin_nontemporal_load(&x[(size_t)(r0 + 2) * 512 + t]);
    float xd = __builtin_nontemporal_load(&x[(size_t)(r0 + 3) * 512 + t]);
    ushort2 pa0 = pairs[t], pa1 = pairs[512 + t];
    ushort2 po0 = pairs[1024 + t], po1 = pairs[1536 + t];
    hx[t]       = cb(__floats2half2_rn(xa, xb));
    hy[t]       = cb(__floats2half2_rn(xc, xd));
    hx[512 + t] = cb(__floats2half2_rn(1.f - xa, 1.f - xb));
    hy[512 + t] = cb(__floats2half2_rn(1.f - xc, 1.f - xd));
    if (t == 0) {
        unsigned int o = cb(__float2half2_rn(1.0f));
        hx[1024] = o; hy[1024] = o;
        hx[1025] = 0u; hy[1025] = 0u;
    }
    __syncthreads();

    {
        uint2 a0 = andg(GAT(pa0.x), GAT(pa0.y));
        uint2 a1 = andg(GAT(pa1.x), GAT(pa1.y));
        uint2 o0 = org(GAT(po0.x), GAT(po0.y));
        uint2 o1 = org(GAT(po1.x), GAT(po1.y));
        PUT(1026 + t, a0); PUT(1538 + t, a1);
        PUT(2050 + t, o0); PUT(2562 + t, o1);
    }
    ushort2 qa0 = pairs[2048 + t], qa1 = pairs[2560 + t];
    ushort2 qo0 = pairs[3072 + t], qo1 = pairs[3584 + t];
    __syncthreads();

    {
        uint2 a0 = andg(GAT(qa0.x), GAT(qa0.y));
        uint2 a1 = andg(GAT(qa1.x), GAT(qa1.y));
        uint2 o0 = org(GAT(qo0.x), GAT(qo0.y));
        uint2 o1 = org(GAT(qo1.x), GAT(qo1.y));
        PUT(3074 + t, a0); PUT(3586 + t, a1);
        PUT(4098 + t, o0); PUT(4610 + t, o1);
    }
    ushort2 za = pairs[4096 + t], zo = pairs[4608 + t];
    float wA = lin_w[t], wO = lin_w[512 + t];
    __syncthreads();

    uint2 cg = andg(GAT(za.x), GAT(za.y));
    uint2 dg = org(GAT(zo.x), GAT(zo.y));
#undef GAT
#undef PUT
    float2 cl = __half22float2(bc(cg.x)), ch2 = __half22float2(bc(cg.y));
    float2 dl = __half22float2(bc(dg.x)), dh = __half22float2(bc(dg.y));
    float4 s;
    s.x = wA * cl.x  + wO * dl.x;
    s.y = wA * cl.y  + wO * dl.y;
    s.z = wA * ch2.x + wO * dh.x;
    s.w = wA * ch2.y + wO * dh.y;

    #pragma unroll
    for (int off = 32; off > 0; off >>= 1) {
        s.x += __shfl_down(s.x, off, 64);
        s.y += __shfl_down(s.y, off, 64);
        s.z += __shfl_down(s.z, off, 64);
        s.w += __shfl_down(s.w, off, 64);
    }
    if ((t & 63) == 0) red[t >> 6] = s;
    __syncthreads();
    if (t == 0) {
        float4 tot = red[0];
        #pragma unroll
        for (int i = 1; i < 8; ++i) {
            tot.x += red[i].x; tot.y += red[i].y;
            tot.z += red[i].z; tot.w += red[i].w;
        }
        *(float4*)(out + r0) = tot;
    }
}

extern "C" void kernel_launch(void* const* d_in, const int* in_sizes, int n_in,
                              void* d_out, int out_size, void* d_ws, size_t ws_size,
                              hipStream_t stream) {
    GatePtrs gp;
    for (int l = 0; l < 3; ++l)
        for (int s = 0; s < 4; ++s) {
            gp.w[l * 4 + s] = (const float*)d_in[l * 8 + s];
            gp.g[l * 4 + s] = (const float*)d_in[l * 8 + 4 + s];
        }
    const float* x     = (const float*)d_in[24];
    const float* lin_w = (const float*)d_in[25];
    float* out = (float*)d_out;

    unsigned long long* packed = (unsigned long long*)d_ws;
    ushort2* pf = (ushort2*)((char*)d_ws + 10240 * 8);
    hipMemsetAsync(d_ws, 0, 10240 * 8, stream);
    if (ws_size >= 10240 * 8 + 20480) {
        argmax_fused<<<588, 512, 0, stream>>>(gp, packed);
        convert_fb<<<20, 256, 0, stream>>>(packed, pf);
        forward_kernel<<<8192, 512, 0, stream>>>(x, lin_w, pf, out);
    } else {
        dim3 ga(2, 81, 12);
        argmax_atomic<<<ga, 256, 0, stream>>>(gp, packed);
        convert_fb<<<20, 256, 0, stream>>>(packed, pf);
        forward_kernel<<<8192, 512, 0, stream>>>(x, lin_w, pf, out);
    }
}

// Round 7
// 348.413 us; speedup vs baseline: 1.0240x; 1.0240x over previous
//
#include <hip/hip_runtime.h>
#include <hip/hip_fp16.h>
#include <stdint.h>

// ---------------------------------------------------------------------------
// RuleModel forward. ST-gumbel gate forward == exact one-hot column selector,
// so each h @ gate is a gather with index argmax_i(w[i,j]+g[i,j]).
// argmax reads are pinned at ~10.8 GB/s/CU (per-CU memory-system limit,
// invariant across 7 concurrency configs, rounds 0-6). Forward's random LDS
// gathers are conflict-bound by RANDOM collisions (layout changes don't help;
// the round-6 hx/hy split cost +18us -> reverted). This round: 32-row chunks
// in argmax (1164 blocks ~ 4.5/CU) to fix the 588-block tail imbalance.
// Pipeline: memset(80KB) -> argmax_fused (32-row chunks, LDS sub-merge,
// atomicMax into 10,240-slot packed table) -> convert_fb -> forward
// (4 rows/block, fp16-packed uint2 h).
// ---------------------------------------------------------------------------

struct GatePtrs {
    const float* w[12];
    const float* g[12];
};

__device__ __forceinline__ unsigned int sortkey(float f) {
    unsigned int u = __float_as_uint(f);
    return u ^ ((u & 0x80000000u) ? 0xFFFFFFFFu : 0x80000000u);
}

// ---------------- fused argmax: block argmax + global atomicMax -------------
// packed layout (u64, 10240 entries): offs[layer] + slot*dout + col.
// value = (sortkey(best) << 32) | (0xFFFFFFFF - best_row)  -> max == best key,
// ties resolved to the SMALLEST row (matches jnp.argmax first-index).
// Flat grid, ONE 512-thread block per (gate, 32-row chunk):
//   L0: blocks [0,132)    = 4 gates x 33 chunks  (2 subs x 16 rows, 256 c4)
//   L1: blocks [132,520)  = 4 gates x 97 chunks  (2 subs x 16 rows, 256 c4)
//   L2: blocks [520,1164) = 4 gates x 161 chunks (4 subs x  8 rows, 128 c4)
__global__ __launch_bounds__(512) void argmax_fused(GatePtrs gp,
                                                    unsigned long long* __restrict__ packed) {
    __shared__ unsigned long long red[1536];   // (subs-1) x cols4 x 4, max 12 KB
    const int dins[3] = {1026, 3074, 5122};
    const int offs[3] = {0, 4096, 8192};
    int bid = blockIdx.x, tid = threadIdx.x;
    int layer, slot, chunk;
    if (bid < 132)      { layer = 0; slot = bid / 33;  chunk = bid - slot * 33; }
    else if (bid < 520) { layer = 1; int r = bid - 132; slot = r / 97;  chunk = r - slot * 97; }
    else                { layer = 2; int r = bid - 520; slot = r / 161; chunk = r - slot * 161; }
    const int gate  = layer * 4 + slot;
    const int din   = dins[layer];
    const int dout  = (layer == 2) ? 512 : 1024;
    const int shift = (layer == 2) ? 7 : 8;     // log2(cols4)
    const int cols4 = 1 << shift;
    const int subs  = 512 >> shift;             // 2 (L0/L1) or 4 (L2)
    const int rps   = 32 / subs;                // rows per sub: 16 or 8
    const int sub   = tid >> shift;
    const int c4    = tid & (cols4 - 1);
    const int s4    = dout >> 2;                // float4s per row
    const int rbeg  = chunk * 32 + sub * rps;
    const int rend  = min(rbeg + rps, din);     // tail chunks: some subs empty

    const float4* __restrict__ wp = (const float4*)gp.w[gate] + (size_t)rbeg * s4 + c4;
    const float4* __restrict__ gq = (const float4*)gp.g[gate] + (size_t)rbeg * s4 + c4;
    // Empty subs keep the -3.4e38 init; sortkey(-3.4e38) is far below any
    // real w+g key (inputs are O(10)), so fake entries never win the merge,
    // and every chunk's sub0 has >=1 real row (chunk*32 < din).
    float bx = -3.4e38f, by = bx, bz = bx, bw = bx;
    int ix = rbeg, iy = rbeg, iz = rbeg, iw = rbeg;
    #pragma unroll 8
    for (int i = rbeg; i < rend; ++i) {
        float4 wv = wp[(size_t)(i - rbeg) * s4];
        float4 gv = gq[(size_t)(i - rbeg) * s4];
        float vx = wv.x + gv.x, vy = wv.y + gv.y;
        float vz = wv.z + gv.z, vw = wv.w + gv.w;
        if (vx > bx) { bx = vx; ix = i; }       // strict > keeps first row
        if (vy > by) { by = vy; iy = i; }
        if (vz > bz) { bz = vz; iz = i; }
        if (vw > bw) { bw = vw; iw = i; }
    }
    unsigned long long e0 = ((unsigned long long)sortkey(bx) << 32) | (unsigned int)ix;
    unsigned long long e1 = ((unsigned long long)sortkey(by) << 32) | (unsigned int)iy;
    unsigned long long e2 = ((unsigned long long)sortkey(bz) << 32) | (unsigned int)iz;
    unsigned long long e3 = ((unsigned long long)sortkey(bw) << 32) | (unsigned int)iw;

    if (sub != 0) {
        unsigned long long* r = red + ((size_t)(sub - 1) * cols4 + c4) * 4;
        r[0] = e0; r[1] = e1; r[2] = e2; r[3] = e3;
    }
    __syncthreads();
    if (sub == 0) {
        // merge ascending-row sub-results; strict > keeps the lowest row on
        // ties (sub s covers strictly lower rows than sub s+1)
        for (int s = 1; s < subs; ++s) {
            const unsigned long long* r = red + ((size_t)(s - 1) * cols4 + c4) * 4;
            unsigned long long o0 = r[0], o1 = r[1], o2 = r[2], o3 = r[3];
            if ((unsigned int)(o0 >> 32) > (unsigned int)(e0 >> 32)) e0 = o0;
            if ((unsigned int)(o1 >> 32) > (unsigned int)(e1 >> 32)) e1 = o1;
            if ((unsigned int)(o2 >> 32) > (unsigned int)(e2 >> 32)) e2 = o2;
            if ((unsigned int)(o3 >> 32) > (unsigned int)(e3 >> 32)) e3 = o3;
        }
        // flip idx to (0xFFFFFFFF - idx): atomicMax then prefers SMALLER rows
        // on equal keys, matching the ordered-merge semantics above.
        unsigned long long* dst = packed + offs[layer] + (size_t)slot * dout + 4 * c4;
        atomicMax(dst + 0, (e0 & 0xFFFFFFFF00000000ull) | (0xFFFFFFFFu - (unsigned int)e0));
        atomicMax(dst + 1, (e1 & 0xFFFFFFFF00000000ull) | (0xFFFFFFFFu - (unsigned int)e1));
        atomicMax(dst + 2, (e2 & 0xFFFFFFFF00000000ull) | (0xFFFFFFFFu - (unsigned int)e2));
        atomicMax(dst + 3, (e3 & 0xFFFFFFFF00000000ull) | (0xFFFFFFFFu - (unsigned int)e3));
    }
}

// ---------------- fallback: atomic argmax (small ws) ------------------------
__global__ __launch_bounds__(256) void argmax_atomic(GatePtrs gp,
                                                     unsigned long long* __restrict__ packed) {
    const int dins[3]  = {1026, 3074, 5122};
    const int douts[3] = {1024, 1024, 512};
    const int offs[3]  = {0, 4096, 8192};
    int gate = blockIdx.z, layer = gate >> 2;
    int din = dins[layer], dout = douts[layer];
    int c2 = blockIdx.x * 256 + threadIdx.x;
    int r0 = blockIdx.y * 64;
    if (2 * c2 >= dout || r0 >= din) return;
    int r1 = min(r0 + 64, din);
    const float* __restrict__ w = gp.w[gate];
    const float* __restrict__ g = gp.g[gate];
    float bx = -3.4e38f, by = -3.4e38f;
    int rx = r0, ry = r0;
    #pragma unroll 8
    for (int i = r0; i < r1; ++i) {
        float2 wv = *(const float2*)(w + (size_t)i * dout + 2 * c2);
        float2 gv = *(const float2*)(g + (size_t)i * dout + 2 * c2);
        float vx = wv.x + gv.x, vy = wv.y + gv.y;
        if (vx > bx) { bx = vx; rx = i; }
        if (vy > by) { by = vy; ry = i; }
    }
    unsigned long long* dst = packed + offs[layer] + (gate & 3) * dout + 2 * c2;
    atomicMax(dst, ((unsigned long long)sortkey(bx) << 32)
                   | (unsigned long long)(0xFFFFFFFFu - (unsigned int)rx));
    atomicMax(dst + 1, ((unsigned long long)sortkey(by) << 32)
                   | (unsigned long long)(0xFFFFFFFFu - (unsigned int)ry));
}

// ---------------- convert packed -> pf (both paths) -------------------------
__global__ __launch_bounds__(256) void convert_fb(const unsigned long long* __restrict__ packed,
                                                  ushort2* __restrict__ pf) {
    int i = blockIdx.x * 256 + threadIdx.x;
    if (i >= 5120) return;
    int l    = (i < 2048) ? 0 : ((i < 4096) ? 1 : 2);
    int half = (l == 2) ? 512 : 1024;
    int r    = i - l * 2048;
    int type = (r >= half) ? 1 : 0;
    int g    = r - type * half;
    int o1   = l * 4096 + 2 * type * half + g;
    int o2   = o1 + half;
    unsigned int i1 = 0xFFFFFFFFu - (unsigned int)(packed[o1] & 0xFFFFFFFFull);
    unsigned int i2 = 0xFFFFFFFFu - (unsigned int)(packed[o2] & 0xFFFFFFFFull);
    pf[i] = make_ushort2((unsigned short)i1, (unsigned short)i2);
}

// ---------------- forward: 4 rows/block, fp16 packed h (round-5 version) ----
__device__ __forceinline__ __half2 bc(unsigned int u) { return __builtin_bit_cast(__half2, u); }
__device__ __forceinline__ unsigned int cb(__half2 h) { return __builtin_bit_cast(unsigned int, h); }

__device__ __forceinline__ uint2 gat(const char* hb, unsigned int s) {
    return *(const uint2*)(hb + (s << 3));
}
__device__ __forceinline__ uint2 andg(uint2 a, uint2 b) {
    return make_uint2(cb(__hmul2(bc(a.x), bc(b.x))), cb(__hmul2(bc(a.y), bc(b.y))));
}
__device__ __forceinline__ uint2 org(uint2 a, uint2 b) {
    __half2 one = __float2half2_rn(1.0f);
    __half2 lo = __hsub2(one, __hmul2(__hsub2(one, bc(a.x)), __hsub2(one, bc(b.x))));
    __half2 hi = __hsub2(one, __hmul2(__hsub2(one, bc(a.y)), __hsub2(one, bc(b.y))));
    return make_uint2(cb(lo), cb(hi));
}

__global__ __launch_bounds__(512) void forward_kernel(const float* __restrict__ x,
                                                      const float* __restrict__ lin_w,
                                                      const ushort2* __restrict__ pairs,
                                                      float* __restrict__ out) {
    __shared__ uint2 h[5122];      // slot s = 4 rows of feature s, fp16 packed
    __shared__ float4 red[8];
    const int t  = threadIdx.x;
    const int r0 = blockIdx.x * 4;
    const char* hb = (const char*)h;

    float xa = x[(size_t)(r0 + 0) * 512 + t];
    float xb = x[(size_t)(r0 + 1) * 512 + t];
    float xc = x[(size_t)(r0 + 2) * 512 + t];
    float xd = x[(size_t)(r0 + 3) * 512 + t];
    ushort2 pa0 = pairs[t], pa1 = pairs[512 + t];
    ushort2 po0 = pairs[1024 + t], po1 = pairs[1536 + t];
    h[t]       = make_uint2(cb(__floats2half2_rn(xa, xb)), cb(__floats2half2_rn(xc, xd)));
    h[512 + t] = make_uint2(cb(__floats2half2_rn(1.f - xa, 1.f - xb)),
                            cb(__floats2half2_rn(1.f - xc, 1.f - xd)));
    if (t == 0) {
        unsigned int o = cb(__float2half2_rn(1.0f));
        h[1024] = make_uint2(o, o);
        h[1025] = make_uint2(0u, 0u);
    }
    __syncthreads();

    {
        uint2 a0 = andg(gat(hb, pa0.x), gat(hb, pa0.y));
        uint2 a1 = andg(gat(hb, pa1.x), gat(hb, pa1.y));
        uint2 o0 = org(gat(hb, po0.x), gat(hb, po0.y));
        uint2 o1 = org(gat(hb, po1.x), gat(hb, po1.y));
        h[1026 + t] = a0; h[1538 + t] = a1;
        h[2050 + t] = o0; h[2562 + t] = o1;
    }
    ushort2 qa0 = pairs[2048 + t], qa1 = pairs[2560 + t];
    ushort2 qo0 = pairs[3072 + t], qo1 = pairs[3584 + t];
    __syncthreads();

    {
        uint2 a0 = andg(gat(hb, qa0.x), gat(hb, qa0.y));
        uint2 a1 = andg(gat(hb, qa1.x), gat(hb, qa1.y));
        uint2 o0 = org(gat(hb, qo0.x), gat(hb, qo0.y));
        uint2 o1 = org(gat(hb, qo1.x), gat(hb, qo1.y));
        h[3074 + t] = a0; h[3586 + t] = a1;
        h[4098 + t] = o0; h[4610 + t] = o1;
    }
    ushort2 za = pairs[4096 + t], zo = pairs[4608 + t];
    float wA = lin_w[t], wO = lin_w[512 + t];
    __syncthreads();

    uint2 cg = andg(gat(hb, za.x), gat(hb, za.y));
    uint2 dg = org(gat(hb, zo.x), gat(hb, zo.y));
    float2 cl = __half22float2(bc(cg.x)), ch2 = __half22float2(bc(cg.y));
    float2 dl = __half22float2(bc(dg.x)), dh = __half22float2(bc(dg.y));
    float4 s;
    s.x = wA * cl.x  + wO * dl.x;
    s.y = wA * cl.y  + wO * dl.y;
    s.z = wA * ch2.x + wO * dh.x;
    s.w = wA * ch2.y + wO * dh.y;

    #pragma unroll
    for (int off = 32; off > 0; off >>= 1) {
        s.x += __shfl_down(s.x, off, 64);
        s.y += __shfl_down(s.y, off, 64);
        s.z += __shfl_down(s.z, off, 64);
        s.w += __shfl_down(s.w, off, 64);
    }
    if ((t & 63) == 0) red[t >> 6] = s;
    __syncthreads();
    if (t == 0) {
        float4 tot = red[0];
        #pragma unroll
        for (int i = 1; i < 8; ++i) {
            tot.x += red[i].x; tot.y += red[i].y;
            tot.z += red[i].z; tot.w += red[i].w;
        }
        *(float4*)(out + r0) = tot;
    }
}

extern "C" void kernel_launch(void* const* d_in, const int* in_sizes, int n_in,
                              void* d_out, int out_size, void* d_ws, size_t ws_size,
                              hipStream_t stream) {
    GatePtrs gp;
    for (int l = 0; l < 3; ++l)
        for (int s = 0; s < 4; ++s) {
            gp.w[l * 4 + s] = (const float*)d_in[l * 8 + s];
            gp.g[l * 4 + s] = (const float*)d_in[l * 8 + 4 + s];
        }
    const float* x     = (const float*)d_in[24];
    const float* lin_w = (const float*)d_in[25];
    float* out = (float*)d_out;

    unsigned long long* packed = (unsigned long long*)d_ws;
    ushort2* pf = (ushort2*)((char*)d_ws + 10240 * 8);
    hipMemsetAsync(d_ws, 0, 10240 * 8, stream);
    if (ws_size >= 10240 * 8 + 20480) {
        argmax_fused<<<1164, 512, 0, stream>>>(gp, packed);
        convert_fb<<<20, 256, 0, stream>>>(packed, pf);
        forward_kernel<<<8192, 512, 0, stream>>>(x, lin_w, pf, out);
    } else {
        dim3 ga(2, 81, 12);
        argmax_atomic<<<ga, 256, 0, stream>>>(gp, packed);
        convert_fb<<<20, 256, 0, stream>>>(packed, pf);
        forward_kernel<<<8192, 512, 0, stream>>>(x, lin_w, pf, out);
    }
}

// Round 8
// 338.375 us; speedup vs baseline: 1.0543x; 1.0297x over previous
//
#include <hip/hip_runtime.h>
#include <hip/hip_fp16.h>
#include <stdint.h>

// ---------------------------------------------------------------------------
// RuleModel forward. ST-gumbel gate forward == exact one-hot column selector,
// so each h @ gate is a gather with index argmax_i(w[i,j]+g[i,j]).
// argmax reads are pinned at ~10.8 GB/s/CU (per-CU memory-system limit,
// invariant across 8 configs: ILP 1-16 deep, TLP 10-21 waves/CU, 256/512
// blocks, fused/unfused). Combine traffic shares the same pipe: 64-row
// chunks (436K atomics ~= 13.6 MB, equal to the partial-write scheme and
// half the 32-row variant) measured best. This file restores the measured
// optimum (round-4 submission, 338.6 us).
// Pipeline: memset(80KB) -> argmax_fused (64-row chunks, LDS sub-merge,
// atomicMax into 10,240-slot packed table) -> convert_fb -> forward
// (4 rows/block, fp16-packed uint2 h).
// ---------------------------------------------------------------------------

struct GatePtrs {
    const float* w[12];
    const float* g[12];
};

__device__ __forceinline__ unsigned int sortkey(float f) {
    unsigned int u = __float_as_uint(f);
    return u ^ ((u & 0x80000000u) ? 0xFFFFFFFFu : 0x80000000u);
}

// ---------------- fused argmax: block argmax + global atomicMax -------------
// packed layout (u64, 10240 entries): offs[layer] + slot*dout + col.
// value = (sortkey(best) << 32) | (0xFFFFFFFF - best_row)  -> max == best key,
// ties resolved to the SMALLEST row (matches jnp.argmax first-index).
// Flat grid, ONE 512-thread block per (gate, 64-row chunk):
//   L0: blocks [0,68)    = 4 gates x 17 chunks (2 subs x 32 rows, 256 c4)
//   L1: blocks [68,264)  = 4 gates x 49 chunks (2 subs x 32 rows, 256 c4)
//   L2: blocks [264,588) = 4 gates x 81 chunks (4 subs x 16 rows, 128 c4)
__global__ __launch_bounds__(512) void argmax_fused(GatePtrs gp,
                                                    unsigned long long* __restrict__ packed) {
    __shared__ unsigned long long red[1536];   // (subs-1) x cols4 x 4, max 12 KB
    const int dins[3] = {1026, 3074, 5122};
    const int offs[3] = {0, 4096, 8192};
    int bid = blockIdx.x, tid = threadIdx.x;
    int layer, slot, chunk;
    if (bid < 68)       { layer = 0; slot = bid / 17;  chunk = bid - slot * 17; }
    else if (bid < 264) { layer = 1; int r = bid - 68;  slot = r / 49; chunk = r - slot * 49; }
    else                { layer = 2; int r = bid - 264; slot = r / 81; chunk = r - slot * 81; }
    const int gate  = layer * 4 + slot;
    const int din   = dins[layer];
    const int dout  = (layer == 2) ? 512 : 1024;
    const int shift = (layer == 2) ? 7 : 8;     // log2(cols4)
    const int cols4 = 1 << shift;
    const int subs  = 512 >> shift;             // 2 (L0/L1) or 4 (L2)
    const int rps   = 64 / subs;                // rows per sub: 32 or 16
    const int sub   = tid >> shift;
    const int c4    = tid & (cols4 - 1);
    const int s4    = dout >> 2;                // float4s per row
    const int rbeg  = chunk * 64 + sub * rps;
    const int rend  = min(rbeg + rps, din);     // tail chunks: some subs empty

    const float4* __restrict__ wp = (const float4*)gp.w[gate] + (size_t)rbeg * s4 + c4;
    const float4* __restrict__ gq = (const float4*)gp.g[gate] + (size_t)rbeg * s4 + c4;
    // Empty subs keep the -3.4e38 init; sortkey(-3.4e38) is far below any
    // real w+g key (inputs are O(10)), so fake entries never win the merge.
    float bx = -3.4e38f, by = bx, bz = bx, bw = bx;
    int ix = rbeg, iy = rbeg, iz = rbeg, iw = rbeg;
    #pragma unroll 8
    for (int i = rbeg; i < rend; ++i) {
        float4 wv = wp[(size_t)(i - rbeg) * s4];
        float4 gv = gq[(size_t)(i - rbeg) * s4];
        float vx = wv.x + gv.x, vy = wv.y + gv.y;
        float vz = wv.z + gv.z, vw = wv.w + gv.w;
        if (vx > bx) { bx = vx; ix = i; }       // strict > keeps first row
        if (vy > by) { by = vy; iy = i; }
        if (vz > bz) { bz = vz; iz = i; }
        if (vw > bw) { bw = vw; iw = i; }
    }
    unsigned long long e0 = ((unsigned long long)sortkey(bx) << 32) | (unsigned int)ix;
    unsigned long long e1 = ((unsigned long long)sortkey(by) << 32) | (unsigned int)iy;
    unsigned long long e2 = ((unsigned long long)sortkey(bz) << 32) | (unsigned int)iz;
    unsigned long long e3 = ((unsigned long long)sortkey(bw) << 32) | (unsigned int)iw;

    if (sub != 0) {
        unsigned long long* r = red + ((size_t)(sub - 1) * cols4 + c4) * 4;
        r[0] = e0; r[1] = e1; r[2] = e2; r[3] = e3;
    }
    __syncthreads();
    if (sub == 0) {
        // merge ascending-row sub-results; strict > keeps the lowest row on
        // ties (sub s covers strictly lower rows than sub s+1)
        for (int s = 1; s < subs; ++s) {
            const unsigned long long* r = red + ((size_t)(s - 1) * cols4 + c4) * 4;
            unsigned long long o0 = r[0], o1 = r[1], o2 = r[2], o3 = r[3];
            if ((unsigned int)(o0 >> 32) > (unsigned int)(e0 >> 32)) e0 = o0;
            if ((unsigned int)(o1 >> 32) > (unsigned int)(e1 >> 32)) e1 = o1;
            if ((unsigned int)(o2 >> 32) > (unsigned int)(e2 >> 32)) e2 = o2;
            if ((unsigned int)(o3 >> 32) > (unsigned int)(e3 >> 32)) e3 = o3;
        }
        // flip idx to (0xFFFFFFFF - idx): atomicMax then prefers SMALLER rows
        // on equal keys, matching the ordered-merge semantics above.
        unsigned long long* dst = packed + offs[layer] + (size_t)slot * dout + 4 * c4;
        atomicMax(dst + 0, (e0 & 0xFFFFFFFF00000000ull) | (0xFFFFFFFFu - (unsigned int)e0));
        atomicMax(dst + 1, (e1 & 0xFFFFFFFF00000000ull) | (0xFFFFFFFFu - (unsigned int)e1));
        atomicMax(dst + 2, (e2 & 0xFFFFFFFF00000000ull) | (0xFFFFFFFFu - (unsigned int)e2));
        atomicMax(dst + 3, (e3 & 0xFFFFFFFF00000000ull) | (0xFFFFFFFFu - (unsigned int)e3));
    }
}

// ---------------- fallback: atomic argmax (small ws) ------------------------
__global__ __launch_bounds__(256) void argmax_atomic(GatePtrs gp,
                                                     unsigned long long* __restrict__ packed) {
    const int dins[3]  = {1026, 3074, 5122};
    const int douts[3] = {1024, 1024, 512};
    const int offs[3]  = {0, 4096, 8192};
    int gate = blockIdx.z, layer = gate >> 2;
    int din = dins[layer], dout = douts[layer];
    int c2 = blockIdx.x * 256 + threadIdx.x;
    int r0 = blockIdx.y * 64;
    if (2 * c2 >= dout || r0 >= din) return;
    int r1 = min(r0 + 64, din);
    const float* __restrict__ w = gp.w[gate];
    const float* __restrict__ g = gp.g[gate];
    float bx = -3.4e38f, by = -3.4e38f;
    int rx = r0, ry = r0;
    #pragma unroll 8
    for (int i = r0; i < r1; ++i) {
        float2 wv = *(const float2*)(w + (size_t)i * dout + 2 * c2);
        float2 gv = *(const float2*)(g + (size_t)i * dout + 2 * c2);
        float vx = wv.x + gv.x, vy = wv.y + gv.y;
        if (vx > bx) { bx = vx; rx = i; }
        if (vy > by) { by = vy; ry = i; }
    }
    unsigned long long* dst = packed + offs[layer] + (gate & 3) * dout + 2 * c2;
    atomicMax(dst, ((unsigned long long)sortkey(bx) << 32)
                   | (unsigned long long)(0xFFFFFFFFu - (unsigned int)rx));
    atomicMax(dst + 1, ((unsigned long long)sortkey(by) << 32)
                   | (unsigned long long)(0xFFFFFFFFu - (unsigned int)ry));
}

// ---------------- convert packed -> pf (both paths) -------------------------
__global__ __launch_bounds__(256) void convert_fb(const unsigned long long* __restrict__ packed,
                                                  ushort2* __restrict__ pf) {
    int i = blockIdx.x * 256 + threadIdx.x;
    if (i >= 5120) return;
    int l    = (i < 2048) ? 0 : ((i < 4096) ? 1 : 2);
    int half = (l == 2) ? 512 : 1024;
    int r    = i - l * 2048;
    int type = (r >= half) ? 1 : 0;
    int g    = r - type * half;
    int o1   = l * 4096 + 2 * type * half + g;
    int o2   = o1 + half;
    unsigned int i1 = 0xFFFFFFFFu - (unsigned int)(packed[o1] & 0xFFFFFFFFull);
    unsigned int i2 = 0xFFFFFFFFu - (unsigned int)(packed[o2] & 0xFFFFFFFFull);
    pf[i] = make_ushort2((unsigned short)i1, (unsigned short)i2);
}

// ---------------- forward: 4 rows/block, fp16 packed h ----------------------
__device__ __forceinline__ __half2 bc(unsigned int u) { return __builtin_bit_cast(__half2, u); }
__device__ __forceinline__ unsigned int cb(__half2 h) { return __builtin_bit_cast(unsigned int, h); }

__device__ __forceinline__ uint2 gat(const char* hb, unsigned int s) {
    return *(const uint2*)(hb + (s << 3));
}
__device__ __forceinline__ uint2 andg(uint2 a, uint2 b) {
    return make_uint2(cb(__hmul2(bc(a.x), bc(b.x))), cb(__hmul2(bc(a.y), bc(b.y))));
}
__device__ __forceinline__ uint2 org(uint2 a, uint2 b) {
    __half2 one = __float2half2_rn(1.0f);
    __half2 lo = __hsub2(one, __hmul2(__hsub2(one, bc(a.x)), __hsub2(one, bc(b.x))));
    __half2 hi = __hsub2(one, __hmul2(__hsub2(one, bc(a.y)), __hsub2(one, bc(b.y))));
    return make_uint2(cb(lo), cb(hi));
}

__global__ __launch_bounds__(512) void forward_kernel(const float* __restrict__ x,
                                                      const float* __restrict__ lin_w,
                                                      const ushort2* __restrict__ pairs,
                                                      float* __restrict__ out) {
    __shared__ uint2 h[5122];      // slot s = 4 rows of feature s, fp16 packed
    __shared__ float4 red[8];
    const int t  = threadIdx.x;
    const int r0 = blockIdx.x * 4;
    const char* hb = (const char*)h;

    float xa = x[(size_t)(r0 + 0) * 512 + t];
    float xb = x[(size_t)(r0 + 1) * 512 + t];
    float xc = x[(size_t)(r0 + 2) * 512 + t];
    float xd = x[(size_t)(r0 + 3) * 512 + t];
    ushort2 pa0 = pairs[t], pa1 = pairs[512 + t];
    ushort2 po0 = pairs[1024 + t], po1 = pairs[1536 + t];
    h[t]       = make_uint2(cb(__floats2half2_rn(xa, xb)), cb(__floats2half2_rn(xc, xd)));
    h[512 + t] = make_uint2(cb(__floats2half2_rn(1.f - xa, 1.f - xb)),
                            cb(__floats2half2_rn(1.f - xc, 1.f - xd)));
    if (t == 0) {
        unsigned int o = cb(__float2half2_rn(1.0f));
        h[1024] = make_uint2(o, o);
        h[1025] = make_uint2(0u, 0u);
    }
    __syncthreads();

    {
        uint2 a0 = andg(gat(hb, pa0.x), gat(hb, pa0.y));
        uint2 a1 = andg(gat(hb, pa1.x), gat(hb, pa1.y));
        uint2 o0 = org(gat(hb, po0.x), gat(hb, po0.y));
        uint2 o1 = org(gat(hb, po1.x), gat(hb, po1.y));
        h[1026 + t] = a0; h[1538 + t] = a1;
        h[2050 + t] = o0; h[2562 + t] = o1;
    }
    ushort2 qa0 = pairs[2048 + t], qa1 = pairs[2560 + t];
    ushort2 qo0 = pairs[3072 + t], qo1 = pairs[3584 + t];
    __syncthreads();

    {
        uint2 a0 = andg(gat(hb, qa0.x), gat(hb, qa0.y));
        uint2 a1 = andg(gat(hb, qa1.x), gat(hb, qa1.y));
        uint2 o0 = org(gat(hb, qo0.x), gat(hb, qo0.y));
        uint2 o1 = org(gat(hb, qo1.x), gat(hb, qo1.y));
        h[3074 + t] = a0; h[3586 + t] = a1;
        h[4098 + t] = o0; h[4610 + t] = o1;
    }
    ushort2 za = pairs[4096 + t], zo = pairs[4608 + t];
    float wA = lin_w[t], wO = lin_w[512 + t];
    __syncthreads();

    uint2 cg = andg(gat(hb, za.x), gat(hb, za.y));
    uint2 dg = org(gat(hb, zo.x), gat(hb, zo.y));
    float2 cl = __half22float2(bc(cg.x)), ch2 = __half22float2(bc(cg.y));
    float2 dl = __half22float2(bc(dg.x)), dh = __half22float2(bc(dg.y));
    float4 s;
    s.x = wA * cl.x  + wO * dl.x;
    s.y = wA * cl.y  + wO * dl.y;
    s.z = wA * ch2.x + wO * dh.x;
    s.w = wA * ch2.y + wO * dh.y;

    #pragma unroll
    for (int off = 32; off > 0; off >>= 1) {
        s.x += __shfl_down(s.x, off, 64);
        s.y += __shfl_down(s.y, off, 64);
        s.z += __shfl_down(s.z, off, 64);
        s.w += __shfl_down(s.w, off, 64);
    }
    if ((t & 63) == 0) red[t >> 6] = s;
    __syncthreads();
    if (t == 0) {
        float4 tot = red[0];
        #pragma unroll
        for (int i = 1; i < 8; ++i) {
            tot.x += red[i].x; tot.y += red[i].y;
            tot.z += red[i].z; tot.w += red[i].w;
        }
        *(float4*)(out + r0) = tot;
    }
}

extern "C" void kernel_launch(void* const* d_in, const int* in_sizes, int n_in,
                              void* d_out, int out_size, void* d_ws, size_t ws_size,
                              hipStream_t stream) {
    GatePtrs gp;
    for (int l = 0; l < 3; ++l)
        for (int s = 0; s < 4; ++s) {
            gp.w[l * 4 + s] = (const float*)d_in[l * 8 + s];
            gp.g[l * 4 + s] = (const float*)d_in[l * 8 + 4 + s];
        }
    const float* x     = (const float*)d_in[24];
    const float* lin_w = (const float*)d_in[25];
    float* out = (float*)d_out;

    unsigned long long* packed = (unsigned long long*)d_ws;
    ushort2* pf = (ushort2*)((char*)d_ws + 10240 * 8);
    hipMemsetAsync(d_ws, 0, 10240 * 8, stream);
    if (ws_size >= 10240 * 8 + 20480) {
        argmax_fused<<<588, 512, 0, stream>>>(gp, packed);
        convert_fb<<<20, 256, 0, stream>>>(packed, pf);
        forward_kernel<<<8192, 512, 0, stream>>>(x, lin_w, pf, out);
    } else {
        dim3 ga(2, 81, 12);
        argmax_atomic<<<ga, 256, 0, stream>>>(gp, packed);
        convert_fb<<<20, 256, 0, stream>>>(packed, pf);
        forward_kernel<<<8192, 512, 0, stream>>>(x, lin_w, pf, out);
    }
}